// Round 4
// baseline (426.407 us; speedup 1.0000x reference)
//
#include <hip/hip_runtime.h>
#include <cstdint>

#define BB 16
#define NN 25200
#define NCLS 80
#define ROW 85
#define MAXDET 300
#define HBINS 2048
#define CAP2 512
#define TGT 448
#define CONF_T 0.25f
#define IOU_T 0.45f
#define NT 512

// ws: box float4[BB*NN] @0 ; score f32[BB*NN] @6451200 ; cls u32[BB*NN] @8064000
static const size_t OFF_SCR = 6451200;
static const size_t OFF_CLS = 8064000;

// Wave-per-row: 2 coalesced dword loads cover the 85-float row; shuffle
// broadcast + shfl_xor max-reduce + ballot/ffs first-occurrence argmax.
// No LDS, tiny VGPR -> full occupancy; latency-hidden streaming.
__global__ __launch_bounds__(256) void k_pre(const float* __restrict__ pred,
                                             float4* __restrict__ boxArr,
                                             float* __restrict__ scoreArr,
                                             unsigned* __restrict__ clsArr) {
    int lane = threadIdx.x & 63;
    int gw = blockIdx.x * 4 + (threadIdx.x >> 6);
    int nw = gridDim.x * 4;
    for (int row = gw; row < BB * NN; row += nw) {
        const float* rp = pred + (size_t)row * ROW;
        float v0 = rp[lane];                               // row[0..63]
        float v1 = (lane < 21) ? rp[64 + lane] : 0.0f;     // row[64..84]
        float obj = __shfl(v0, 4);
        // candidate products (exact: __fmul_rn(cls, obj), same as reference)
        float c0 = (lane >= 5) ? __fmul_rn(v0, obj) : -1.0f;   // cls idx lane-5 (0..58)
        float c1 = (lane < 21) ? __fmul_rn(v1, obj) : -1.0f;   // cls idx 59+lane (59..79)
        float mx = fmaxf(c0, c1);
        for (int d = 1; d < 64; d <<= 1)
            mx = fmaxf(mx, __shfl_xor(mx, d));
        // first-occurrence argmax: c0 indices all < c1 indices; both lane-ordered
        unsigned long long m0 = __ballot(c0 == mx);
        unsigned long long m1 = __ballot(c1 == mx);
        int bj = m0 ? (__ffsll(m0) - 6) : (__ffsll(m1) + 58);
        float cx = __shfl(v0, 0), cy = __shfl(v0, 1);
        float w  = __shfl(v0, 2), h  = __shfl(v0, 3);
        if (lane == 0) {
            float hw = __fmul_rn(w, 0.5f), hh = __fmul_rn(h, 0.5f);
            float4 bx = make_float4(__fsub_rn(cx, hw), __fsub_rn(cy, hh),
                                    __fadd_rn(cx, hw), __fadd_rn(cy, hh));
            bool valid = (obj > CONF_T) && (mx > CONF_T);
            boxArr[row] = bx;
            scoreArr[row] = valid ? mx : -1.0f;
            clsArr[row] = (unsigned)bj;
        }
    }
}

// One block/image, 512 threads. ZERO private-array dynamic indexing (no scratch):
// hist -> threshold -> compact(u64 keys) -> bitonic -> gather -> forward-only
// pairwise mask -> lane-distributed register resolve -> rank scatter -> outputs.
__global__ __launch_bounds__(NT) void k_nms(const float4* __restrict__ boxArr,
                                            const unsigned* __restrict__ clsArr,
                                            const float* __restrict__ logits,
                                            const float* __restrict__ scoreArr,
                                            float* __restrict__ out) {
    __shared__ __align__(16) char smem[63776];
    unsigned* hist = (unsigned*)smem;                               // [2048] (phase A)
    unsigned* csum = (unsigned*)(smem + 8192);                      // [257]  (phase A)
    unsigned long long* mask = (unsigned long long*)smem;           // [512*8] (phase B overlay)
    unsigned long long* keys = (unsigned long long*)(smem + 32768); // [512]
    float4*   cbox   = (float4*)(smem + 36864);                     // [512]
    float4*   rawbox = (float4*)(smem + 45056);                     // [512]
    unsigned* ccls   = (unsigned*)(smem + 53248);                   // [512]
    float4*   rowbox = (float4*)(smem + 55296);                     // [300]
    float*    rowscore = (float*)(smem + 60096);                    // [300]
    unsigned* rowcls = (unsigned*)(smem + 61296);                   // [300]
    unsigned* rowsrc = (unsigned*)(smem + 62496);                   // [300]
    unsigned long long* keepm = (unsigned long long*)(smem + 63696);// [8]
    int*      flags  = (int*)(smem + 63760);                        // cnt, thr, kept

    int b = blockIdx.x, tid = threadIdx.x;

    for (int k = tid; k < HBINS; k += NT) hist[k] = 0u;
    if (tid == 0) { flags[0] = 0; flags[1] = 0; }
    __syncthreads();

    // phase 1: histogram of score bit-bins (LDS atomics)
    for (int n = tid; n < NN; n += NT) {
        float s = scoreArr[(size_t)b * NN + n];
        if (s > 0.0f) {
            unsigned key = (__float_as_uint(s) - 0x3E800000u) >> 13;
            if (key > HBINS - 1) key = HBINS - 1;
            atomicAdd(&hist[key], 1u);
        }
    }
    __syncthreads();

    // phase 2: suffix scan -> threshold bin (verified r2/r3 logic)
    if (tid < 256) {
        unsigned cs = 0;
#pragma unroll
        for (int t = 0; t < 8; ++t) cs += hist[tid * 8 + t];
        csum[tid] = cs;
    }
    __syncthreads();
    for (int off = 1; off < 256; off <<= 1) {
        unsigned v = 0, add = 0;
        if (tid < 256) {
            v = csum[tid];
            add = (tid + off < 256) ? csum[tid + off] : 0u;
        }
        __syncthreads();
        if (tid < 256) csum[tid] = v + add;
        __syncthreads();
    }
    if (tid < 256) {
        unsigned Sc = csum[tid];
        unsigned Sn = (tid < 255) ? csum[tid + 1] : 0u;
        if (Sc >= TGT && (tid == 255 || Sn < TGT)) {
            unsigned cum = Sn;
            int t = tid * 8;
            for (int k = tid * 8 + 7; k >= tid * 8; --k) {
                cum += hist[k];
                if (cum >= TGT) { t = k; break; }
            }
            flags[1] = t;
        }
    }
    __syncthreads();
    unsigned thr = (unsigned)flags[1];

    // phase 3: compact into u64 keys = (scorebits<<32) | (0xFFFFFFFF - idx)
    // descending key order == (score desc, idx asc) — exact reference order
    for (int n = tid; n < NN; n += NT) {
        float s = scoreArr[(size_t)b * NN + n];
        if (s > 0.0f) {
            unsigned key = (__float_as_uint(s) - 0x3E800000u) >> 13;
            if (key > HBINS - 1) key = HBINS - 1;
            if (key >= thr) {
                int pos = atomicAdd(&flags[0], 1);
                if (pos < CAP2)
                    keys[pos] = ((unsigned long long)__float_as_uint(s) << 32)
                              | (unsigned long long)(0xFFFFFFFFu - (unsigned)n);
            }
        }
    }
    __syncthreads();
    int c = min(flags[0], CAP2);
    for (int p = tid; p < CAP2; p += NT)
        if (p >= c) keys[p] = 0ULL;
    __syncthreads();

    // phase 4: bitonic sort 512 u64 keys, descending
    for (int k = 2; k <= CAP2; k <<= 1) {
        for (int j = k >> 1; j > 0; j >>= 1) {
            for (int i = tid; i < CAP2; i += NT) {
                int ixj = i ^ j;
                if (ixj > i) {
                    unsigned long long k1 = keys[i], k2 = keys[ixj];
                    bool sw = ((i & k) == 0) ? (k1 < k2) : (k1 > k2);
                    if (sw) { keys[i] = k2; keys[ixj] = k1; }
                }
            }
            __syncthreads();
        }
    }

    // phase 5: gather raw + class-offset boxes
    for (int p = tid; p < CAP2; p += NT) {
        if (p < c) {
            int n = (int)(0xFFFFFFFFu - (unsigned)keys[p]);
            float4 bb = boxArr[(size_t)b * NN + n];
            unsigned cl = clsArr[(size_t)b * NN + n];
            rawbox[p] = bb;
            float off = __fmul_rn((float)cl, 4096.0f);
            cbox[p] = make_float4(__fadd_rn(bb.x, off), __fadd_rn(bb.y, off),
                                  __fadd_rn(bb.z, off), __fadd_rn(bb.w, off));
            ccls[p] = cl;
        } else {
            rawbox[p] = make_float4(0.f, 0.f, 0.f, 0.f);
            cbox[p]   = make_float4(0.f, 0.f, 0.f, 0.f);
            ccls[p] = 0u;
        }
    }
    __syncthreads();

    // phase 6: forward-only pairwise suppression bits (j > i only)
    for (int task = tid; task < CAP2 * 8; task += NT) {
        int i = task & (CAP2 - 1);
        int w = task >> 9;
        int jbase = w << 6;
        unsigned long long m = 0ULL;
        if (i < c && jbase + 63 > i) {
            float4 ci = cbox[i];
            float a1 = __fmul_rn(__fsub_rn(ci.z, ci.x), __fsub_rn(ci.w, ci.y));
#pragma unroll 4
            for (int jj = 0; jj < 64; ++jj) {
                int j = jbase + jj;
                float4 cj = cbox[j];  // uniform address -> broadcast
                float ltx = fmaxf(ci.x, cj.x), lty = fmaxf(ci.y, cj.y);
                float rbx = fminf(ci.z, cj.z), rby = fminf(ci.w, cj.w);
                float ww = fmaxf(__fsub_rn(rbx, ltx), 0.0f);
                float hh = fmaxf(__fsub_rn(rby, lty), 0.0f);
                float inter = __fmul_rn(ww, hh);
                if (j > i && inter > 0.0f) {
                    float a2 = __fmul_rn(__fsub_rn(cj.z, cj.x), __fsub_rn(cj.w, cj.y));
                    float denom = __fadd_rn(__fsub_rn(__fadd_rn(a1, a2), inter), 1e-9f);
                    if (inter / denom > IOU_T) m |= (1ULL << jj);
                }
            }
        }
        mask[i * 8 + w] = m;
    }
    __syncthreads();

    // phase 7: greedy resolve on wave 0. rem word q lives in lane q's REGISTER
    // (no scratch); word test via shuffle; mask row read by lanes 0..7 parallel.
    if (tid < 64) {
        int lane = tid;
        unsigned long long remq = 0ULL, kpq = 0ULL;
        int kept = 0;
        for (int p = 0; p < c && kept < MAXDET; ++p) {
            int w = p >> 6, bitp = p & 63;
            unsigned long long tw = __shfl(remq, w);
            if (!((tw >> bitp) & 1ULL)) {
                if (lane < 8) remq |= mask[p * 8 + lane];
                if (lane == w) kpq |= (1ULL << bitp);
                kept++;
            }
        }
        if (lane < 8) keepm[lane] = kpq;
        if (lane == 0) flags[2] = kept;
    }
    __syncthreads();
    int kept = flags[2];

    // phase 8: rank-scatter kept rows (keepm read from LDS — dynamic LDS ok)
    for (int p = tid; p < c; p += NT) {
        int w = p >> 6, bitp = p & 63;
        unsigned long long kw = keepm[w];
        if ((kw >> bitp) & 1ULL) {
            int rank = __popcll(kw & ((1ULL << bitp) - 1ULL));
#pragma unroll
            for (int q = 0; q < 8; ++q) rank += (q < w) ? __popcll(keepm[q]) : 0;
            if (rank < MAXDET) {
                rowbox[rank] = rawbox[p];
                rowscore[rank] = __uint_as_float((unsigned)(keys[p] >> 32));
                rowcls[rank] = ccls[p];
                rowsrc[rank] = 0xFFFFFFFFu - (unsigned)keys[p];
            }
        }
    }
    __syncthreads();

    // phase 9: outputs — every element written (d_out re-poisoned each launch)
    float* dets = out;
    float* lg   = out + (size_t)BB * MAXDET * 6;
    float* kpo  = lg  + (size_t)BB * MAXDET * NCLS;

    for (int i = tid; i < MAXDET * 6; i += NT) {
        int t = i / 6, col = i - t * 6;
        float v = 0.0f;
        if (t < kept) {
            if (col < 4)       v = ((const float*)&rowbox[t])[col];
            else if (col == 4) v = rowscore[t];
            else               v = (float)rowcls[t];
        }
        dets[(size_t)b * MAXDET * 6 + i] = v;
    }
    for (int i = tid; i < MAXDET; i += NT)
        kpo[b * MAXDET + i] = (i < kept) ? 1.0f : 0.0f;
    for (int i = tid; i < MAXDET * NCLS; i += NT) {
        int t = i / NCLS, col = i - t * NCLS;
        float v = 0.0f;
        if (t < kept) v = logits[((size_t)b * NN + rowsrc[t]) * NCLS + col];
        lg[(size_t)b * MAXDET * NCLS + i] = v;
    }
}

extern "C" void kernel_launch(void* const* d_in, const int* in_sizes, int n_in,
                              void* d_out, int out_size, void* d_ws, size_t ws_size,
                              hipStream_t stream) {
    const float* pred   = (const float*)d_in[0];
    const float* logits = (const float*)d_in[1];
    float* out = (float*)d_out;
    char* ws = (char*)d_ws;

    float4*   box = (float4*)ws;
    float*    scr = (float*)(ws + OFF_SCR);
    unsigned* cls = (unsigned*)(ws + OFF_CLS);

    // 2520 blocks * 4 waves = 10080 waves; 403200/10080 = 40 rows/wave exact
    k_pre<<<2520, 256, 0, stream>>>(pred, box, scr, cls);
    k_nms<<<BB, NT, 0, stream>>>(box, cls, logits, scr, out);
}

// Round 5
// 388.431 us; speedup vs baseline: 1.0978x; 1.0978x over previous
//
#include <hip/hip_runtime.h>
#include <cstdint>

#define BB 16
#define NN 25200
#define NCLS 80
#define ROW 85
#define MAXDET 300
#define HBINS 2048
#define CAP2 512
#define TGT 448
#define CONF_T 0.25f
#define IOU_T 0.45f
#define NT 1024

// ws: score f32[BB*NN] @ 0  (1.6MB) — box/cls re-derived in k_nms for top-512 only
// Wave-per-row, score only: 2 coalesced loads, products, 6-step shfl_xor max
// reduce, lane0 stores one float. Minimal DS ops, minimal writes.
__global__ __launch_bounds__(256) void k_pre(const float* __restrict__ pred,
                                             float* __restrict__ scoreArr) {
    int lane = threadIdx.x & 63;
    int gw = blockIdx.x * 4 + (threadIdx.x >> 6);
    int nw = gridDim.x * 4;
    for (int row = gw; row < BB * NN; row += nw) {
        const float* rp = pred + (size_t)row * ROW;
        float v0 = rp[lane];                            // row[0..63]
        float v1 = (lane < 21) ? rp[64 + lane] : 0.0f;  // row[64..84]
        float obj = __shfl(v0, 4);
        float c0 = (lane >= 5) ? __fmul_rn(v0, obj) : -1.0f;  // cls 0..58
        float c1 = (lane < 21) ? __fmul_rn(v1, obj) : -1.0f;  // cls 59..79
        float mx = fmaxf(c0, c1);
        for (int d = 1; d < 64; d <<= 1)
            mx = fmaxf(mx, __shfl_xor(mx, d));
        if (lane == 0) {
            bool valid = (obj > CONF_T) && (mx > CONF_T);
            scoreArr[row] = valid ? mx : -1.0f;
        }
    }
}

// One block/image, 1024 threads. hist -> threshold -> compact(u64 keys) ->
// bitonic 512 -> per-candidate recompute (argmax/box from pred, L3-hot) ->
// forward-only pairwise mask -> wave0 register resolve -> rank scatter -> out.
__global__ __launch_bounds__(NT) void k_nms(const float* __restrict__ pred,
                                            const float* __restrict__ logits,
                                            const float* __restrict__ scoreArr,
                                            float* __restrict__ out) {
    __shared__ __align__(16) char smem[63776];
    unsigned* hist = (unsigned*)smem;                               // [2048] phase A
    unsigned* csum = (unsigned*)(smem + 8192);                      // [257]  phase A
    unsigned long long* mask = (unsigned long long*)smem;           // [512*8] phase B overlay
    unsigned long long* keys = (unsigned long long*)(smem + 32768); // [512]
    float4*   cbox   = (float4*)(smem + 36864);                     // [512] offset boxes
    float4*   rawbox = (float4*)(smem + 45056);                     // [512]
    unsigned* ccls   = (unsigned*)(smem + 53248);                   // [512]
    float4*   rowbox = (float4*)(smem + 55296);                     // [300]
    float*    rowscore = (float*)(smem + 60096);                    // [300]
    unsigned* rowcls = (unsigned*)(smem + 61296);                   // [300]
    unsigned* rowsrc = (unsigned*)(smem + 62496);                   // [300]
    unsigned long long* keepm = (unsigned long long*)(smem + 63696);// [8]
    int*      flags  = (int*)(smem + 63760);                        // cnt, thr, kept

    int b = blockIdx.x, tid = threadIdx.x;

    for (int k = tid; k < HBINS; k += NT) hist[k] = 0u;
    if (tid == 0) { flags[0] = 0; flags[1] = 0; }
    __syncthreads();

    // phase 1: histogram of score bit-bins (coalesced reads, LDS atomics)
    for (int n = tid; n < NN; n += NT) {
        float s = scoreArr[(size_t)b * NN + n];
        if (s > 0.0f) {
            unsigned key = (__float_as_uint(s) - 0x3E800000u) >> 13;
            if (key > HBINS - 1) key = HBINS - 1;
            atomicAdd(&hist[key], 1u);
        }
    }
    __syncthreads();

    // phase 2: suffix scan -> threshold bin (verified r2-r4 logic)
    if (tid < 256) {
        unsigned cs = 0;
#pragma unroll
        for (int t = 0; t < 8; ++t) cs += hist[tid * 8 + t];
        csum[tid] = cs;
    }
    __syncthreads();
    for (int off = 1; off < 256; off <<= 1) {
        unsigned v = 0, add = 0;
        if (tid < 256) {
            v = csum[tid];
            add = (tid + off < 256) ? csum[tid + off] : 0u;
        }
        __syncthreads();
        if (tid < 256) csum[tid] = v + add;
        __syncthreads();
    }
    if (tid < 256) {
        unsigned Sc = csum[tid];
        unsigned Sn = (tid < 255) ? csum[tid + 1] : 0u;
        if (Sc >= TGT && (tid == 255 || Sn < TGT)) {
            unsigned cum = Sn;
            int t = tid * 8;
            for (int k = tid * 8 + 7; k >= tid * 8; --k) {
                cum += hist[k];
                if (cum >= TGT) { t = k; break; }
            }
            flags[1] = t;
        }
    }
    __syncthreads();
    unsigned thr = (unsigned)flags[1];

    // phase 3: compact into u64 keys = (scorebits<<32)|(~idx) — desc key order
    // == (score desc, idx asc), the exact reference ordering
    for (int n = tid; n < NN; n += NT) {
        float s = scoreArr[(size_t)b * NN + n];
        if (s > 0.0f) {
            unsigned key = (__float_as_uint(s) - 0x3E800000u) >> 13;
            if (key > HBINS - 1) key = HBINS - 1;
            if (key >= thr) {
                int pos = atomicAdd(&flags[0], 1);
                if (pos < CAP2)
                    keys[pos] = ((unsigned long long)__float_as_uint(s) << 32)
                              | (unsigned long long)(0xFFFFFFFFu - (unsigned)n);
            }
        }
    }
    __syncthreads();
    int c = min(flags[0], CAP2);
    for (int p = tid; p < CAP2; p += NT)
        if (p >= c) keys[p] = 0ULL;
    __syncthreads();

    // phase 4: bitonic sort 512 u64 keys, descending
    for (int k = 2; k <= CAP2; k <<= 1) {
        for (int j = k >> 1; j > 0; j >>= 1) {
            for (int i = tid; i < CAP2; i += NT) {
                int ixj = i ^ j;
                if (ixj > i) {
                    unsigned long long k1 = keys[i], k2 = keys[ixj];
                    bool sw = ((i & k) == 0) ? (k1 < k2) : (k1 > k2);
                    if (sw) { keys[i] = k2; keys[ixj] = k1; }
                }
            }
            __syncthreads();
        }
    }

    // phase 5: per-candidate recompute from pred (rows are L3-resident).
    // Bitwise-identical products/argmax/box as reference; first-occurrence argmax.
    if (tid < CAP2) {
        int p = tid;
        if (p < c) {
            int n = (int)(0xFFFFFFFFu - (unsigned)keys[p]);
            const float* rp = pred + ((size_t)b * NN + n) * ROW;
            float cx = rp[0], cy = rp[1], w = rp[2], h = rp[3], obj = rp[4];
            float best = __fmul_rn(rp[5], obj);
            int bj = 0;
#pragma unroll 8
            for (int cc = 1; cc < NCLS; ++cc) {
                float v = __fmul_rn(rp[5 + cc], obj);
                if (v > best) { best = v; bj = cc; }
            }
            float hw = __fmul_rn(w, 0.5f), hh = __fmul_rn(h, 0.5f);
            float4 bb = make_float4(__fsub_rn(cx, hw), __fsub_rn(cy, hh),
                                    __fadd_rn(cx, hw), __fadd_rn(cy, hh));
            rawbox[p] = bb;
            float off = __fmul_rn((float)bj, 4096.0f);
            cbox[p] = make_float4(__fadd_rn(bb.x, off), __fadd_rn(bb.y, off),
                                  __fadd_rn(bb.z, off), __fadd_rn(bb.w, off));
            ccls[p] = (unsigned)bj;
        } else {
            rawbox[p] = make_float4(0.f, 0.f, 0.f, 0.f);
            cbox[p]   = make_float4(0.f, 0.f, 0.f, 0.f);
            ccls[p] = 0u;
        }
    }
    __syncthreads();

    // phase 6: forward-only pairwise suppression bits (j > i only)
    for (int task = tid; task < CAP2 * 8; task += NT) {
        int i = task & (CAP2 - 1);
        int w = task >> 9;
        int jbase = w << 6;
        unsigned long long m = 0ULL;
        if (i < c && jbase + 63 > i) {
            float4 ci = cbox[i];
            float a1 = __fmul_rn(__fsub_rn(ci.z, ci.x), __fsub_rn(ci.w, ci.y));
#pragma unroll 4
            for (int jj = 0; jj < 64; ++jj) {
                int j = jbase + jj;
                float4 cj = cbox[j];  // uniform address -> broadcast
                float ltx = fmaxf(ci.x, cj.x), lty = fmaxf(ci.y, cj.y);
                float rbx = fminf(ci.z, cj.z), rby = fminf(ci.w, cj.w);
                float ww = fmaxf(__fsub_rn(rbx, ltx), 0.0f);
                float hh = fmaxf(__fsub_rn(rby, lty), 0.0f);
                float inter = __fmul_rn(ww, hh);
                if (j > i && inter > 0.0f) {
                    float a2 = __fmul_rn(__fsub_rn(cj.z, cj.x), __fsub_rn(cj.w, cj.y));
                    float denom = __fadd_rn(__fsub_rn(__fadd_rn(a1, a2), inter), 1e-9f);
                    if (inter / denom > IOU_T) m |= (1ULL << jj);
                }
            }
        }
        mask[i * 8 + w] = m;
    }
    __syncthreads();

    // phase 7: greedy resolve on wave 0. rem word q lives in lane q's register;
    // word test via shuffle; mask row read by 8 lanes in parallel. No scratch.
    if (tid < 64) {
        int lane = tid;
        unsigned long long remq = 0ULL, kpq = 0ULL;
        int kept = 0;
        for (int p = 0; p < c && kept < MAXDET; ++p) {
            int w = p >> 6, bitp = p & 63;
            unsigned long long tw = __shfl(remq, w);
            if (!((tw >> bitp) & 1ULL)) {
                if (lane < 8) remq |= mask[p * 8 + lane];
                if (lane == w) kpq |= (1ULL << bitp);
                kept++;
            }
        }
        if (lane < 8) keepm[lane] = kpq;
        if (lane == 0) flags[2] = kept;
    }
    __syncthreads();
    int kept = flags[2];

    // phase 8: rank-scatter kept rows into dense [0,kept)
    for (int p = tid; p < c; p += NT) {
        int w = p >> 6, bitp = p & 63;
        unsigned long long kw = keepm[w];
        if ((kw >> bitp) & 1ULL) {
            int rank = __popcll(kw & ((1ULL << bitp) - 1ULL));
#pragma unroll
            for (int q = 0; q < 8; ++q) rank += (q < w) ? __popcll(keepm[q]) : 0;
            if (rank < MAXDET) {
                rowbox[rank] = rawbox[p];
                rowscore[rank] = __uint_as_float((unsigned)(keys[p] >> 32));
                rowcls[rank] = ccls[p];
                rowsrc[rank] = 0xFFFFFFFFu - (unsigned)keys[p];
            }
        }
    }
    __syncthreads();

    // phase 9: outputs — every element written (d_out re-poisoned each launch)
    float* dets = out;
    float* lg   = out + (size_t)BB * MAXDET * 6;
    float* kpo  = lg  + (size_t)BB * MAXDET * NCLS;

    for (int i = tid; i < MAXDET * 6; i += NT) {
        int t = i / 6, col = i - t * 6;
        float v = 0.0f;
        if (t < kept) {
            if (col < 4)       v = ((const float*)&rowbox[t])[col];
            else if (col == 4) v = rowscore[t];
            else               v = (float)rowcls[t];
        }
        dets[(size_t)b * MAXDET * 6 + i] = v;
    }
    for (int i = tid; i < MAXDET; i += NT)
        kpo[b * MAXDET + i] = (i < kept) ? 1.0f : 0.0f;
    for (int i = tid; i < MAXDET * NCLS; i += NT) {
        int t = i / NCLS, col = i - t * NCLS;
        float v = 0.0f;
        if (t < kept) v = logits[((size_t)b * NN + rowsrc[t]) * NCLS + col];
        lg[(size_t)b * MAXDET * NCLS + i] = v;
    }
}

extern "C" void kernel_launch(void* const* d_in, const int* in_sizes, int n_in,
                              void* d_out, int out_size, void* d_ws, size_t ws_size,
                              hipStream_t stream) {
    const float* pred   = (const float*)d_in[0];
    const float* logits = (const float*)d_in[1];
    float* out = (float*)d_out;
    float* scr = (float*)d_ws;

    // 2520 blocks * 4 waves = 10080 waves; 403200/10080 = 40 rows/wave exact
    k_pre<<<2520, 256, 0, stream>>>(pred, scr);
    k_nms<<<BB, NT, 0, stream>>>(pred, logits, scr, out);
}

// Round 6
// 346.935 us; speedup vs baseline: 1.2291x; 1.1196x over previous
//
#include <hip/hip_runtime.h>
#include <cstdint>

#define BB 16
#define NN 25200
#define NCLS 80
#define ROW 85
#define MAXDET 300
#define HBINS 2048
#define CAP2 512
#define TGT 448
#define CONF_T 0.25f
#define IOU_T 0.45f
#define NT 1024

// ---------------- workspace layout (bytes) ----------------
static const size_t OFF_KEYS  = 1612800;            // u64  [BB][512] sorted keys
static const size_t OFF_CBOX  = OFF_KEYS  + 65536;  // f4   [BB][512] class-offset boxes
static const size_t OFF_RAW   = OFF_CBOX  + 131072; // f4   [BB][512] raw boxes
static const size_t OFF_CCLS  = OFF_RAW   + 131072; // u32  [BB][512]
static const size_t OFF_CCNT  = OFF_CCLS  + 32768;  // i32  [BB]
static const size_t OFF_MASK  = OFF_CCNT  + 64;     // u64  [BB][512][8] row-major suppression
static const size_t OFF_MASKT = OFF_MASK  + 524288; // u64  [BB][8][64]  transposed diagonal blocks

// 4 lanes per row: lane t of quad reads cols {0..21,22..42,43..63,64..84},
// local first-occurrence argmax of cls*obj, 2-step quad shfl reduce.
__global__ __launch_bounds__(256) void k_pre(const float* __restrict__ pred,
                                             float* __restrict__ scoreArr) {
    int tid = threadIdx.x;
    int t = tid & 3;
    int row = blockIdx.x * 64 + (tid >> 2);
    const float* rp = pred + (size_t)row * ROW;
    int start = (t == 0) ? 0 : (1 + 21 * t);   // 0,22,43,64
    int cnt   = (t == 0) ? 22 : 21;
    float obj = rp[4];                          // quad-broadcast load
    float best = -1.0f; int bc = 1 << 20;
#pragma unroll
    for (int k = 0; k < 22; ++k) {
        if (k < cnt) {
            int col = start + k;
            if (col >= 5) {
                float v = __fmul_rn(rp[col], obj);
                if (v > best) { best = v; bc = col; }
            }
        }
    }
#pragma unroll
    for (int d = 1; d <= 2; d <<= 1) {
        float ob = __shfl_xor(best, d);
        int   oc = __shfl_xor(bc, d);
        if (ob > best || (ob == best && oc < bc)) { best = ob; bc = oc; }
    }
    if (t == 0) {
        bool valid = (obj > CONF_T) && (best > CONF_T);
        scoreArr[row] = valid ? best : -1.0f;
    }
}

// 16 blocks x 1024: hist(reg-cached scores) -> threshold -> wave-aggregated
// compact -> bitonic 512 -> per-candidate recompute -> write candidates to ws.
__global__ __launch_bounds__(NT) void k_sel(const float* __restrict__ pred,
                                            const float* __restrict__ scoreArr,
                                            unsigned long long* __restrict__ keysG,
                                            float4* __restrict__ cboxG,
                                            float4* __restrict__ rawG,
                                            unsigned* __restrict__ cclsG,
                                            int* __restrict__ ccnt) {
    __shared__ unsigned hist[HBINS];
    __shared__ unsigned csum[257];
    __shared__ unsigned long long keys[CAP2];
    __shared__ int flags[2];  // 0=cnt 1=thr

    int b = blockIdx.x, tid = threadIdx.x;
    int lane = tid & 63;

    for (int k = tid; k < HBINS; k += NT) hist[k] = 0u;
    if (tid == 0) { flags[0] = 0; flags[1] = 0; }
    __syncthreads();

    // phase 1: register-cache scores + LDS histogram
    float sreg[25];
#pragma unroll
    for (int t = 0; t < 25; ++t) {
        int n = tid + t * NT;
        float s = (n < NN) ? scoreArr[(size_t)b * NN + n] : -1.0f;
        sreg[t] = s;
        if (s > 0.0f) {
            unsigned key = (__float_as_uint(s) - 0x3E800000u) >> 13;
            if (key > HBINS - 1) key = HBINS - 1;
            atomicAdd(&hist[key], 1u);
        }
    }
    __syncthreads();

    // phase 2: suffix scan -> threshold bin (verified r2-r5 logic)
    if (tid < 256) {
        unsigned cs = 0;
#pragma unroll
        for (int t = 0; t < 8; ++t) cs += hist[tid * 8 + t];
        csum[tid] = cs;
    }
    __syncthreads();
    for (int off = 1; off < 256; off <<= 1) {
        unsigned v = 0, add = 0;
        if (tid < 256) {
            v = csum[tid];
            add = (tid + off < 256) ? csum[tid + off] : 0u;
        }
        __syncthreads();
        if (tid < 256) csum[tid] = v + add;
        __syncthreads();
    }
    if (tid < 256) {
        unsigned Sc = csum[tid];
        unsigned Sn = (tid < 255) ? csum[tid + 1] : 0u;
        if (Sc >= TGT && (tid == 255 || Sn < TGT)) {
            unsigned cum = Sn;
            int t = tid * 8;
            for (int k = tid * 8 + 7; k >= tid * 8; --k) {
                cum += hist[k];
                if (cum >= TGT) { t = k; break; }
            }
            flags[1] = t;
        }
    }
    __syncthreads();
    unsigned thr = (unsigned)flags[1];

    // phase 3: wave-aggregated compaction (1 atomic per wave per round)
#pragma unroll
    for (int t = 0; t < 25; ++t) {
        int n = tid + t * NT;
        float s = sreg[t];
        bool win = false;
        if (s > 0.0f) {
            unsigned key = (__float_as_uint(s) - 0x3E800000u) >> 13;
            if (key > HBINS - 1) key = HBINS - 1;
            win = (key >= thr);
        }
        unsigned long long m = __ballot(win);
        if (m) {
            int lead = __ffsll((long long)m) - 1;
            int base = 0;
            if (lane == lead) base = atomicAdd(&flags[0], __popcll(m));
            base = __shfl(base, lead);
            if (win) {
                int pos = base + __popcll(m & ((1ULL << lane) - 1ULL));
                if (pos < CAP2)
                    keys[pos] = ((unsigned long long)__float_as_uint(s) << 32)
                              | (unsigned long long)(0xFFFFFFFFu - (unsigned)n);
            }
        }
    }
    __syncthreads();
    int c = min(flags[0], CAP2);
    for (int p = tid; p < CAP2; p += NT)
        if (p >= c) keys[p] = 0ULL;
    __syncthreads();

    // phase 4: bitonic sort 512 u64 desc == (score desc, idx asc)
    for (int k = 2; k <= CAP2; k <<= 1) {
        for (int j = k >> 1; j > 0; j >>= 1) {
            for (int i = tid; i < CAP2; i += NT) {
                int ixj = i ^ j;
                if (ixj > i) {
                    unsigned long long k1 = keys[i], k2 = keys[ixj];
                    bool sw = ((i & k) == 0) ? (k1 < k2) : (k1 > k2);
                    if (sw) { keys[i] = k2; keys[ixj] = k1; }
                }
            }
            __syncthreads();
        }
    }

    // phase 5: recompute argmax/box for sorted candidates (bitwise = reference)
    if (tid < CAP2) {
        int p = tid;
        if (p < c) {
            int n = (int)(0xFFFFFFFFu - (unsigned)keys[p]);
            const float* rp = pred + ((size_t)b * NN + n) * ROW;
            float cx = rp[0], cy = rp[1], w = rp[2], h = rp[3], obj = rp[4];
            float best = __fmul_rn(rp[5], obj);
            int bj = 0;
#pragma unroll 8
            for (int cc = 1; cc < NCLS; ++cc) {
                float v = __fmul_rn(rp[5 + cc], obj);
                if (v > best) { best = v; bj = cc; }
            }
            float hw = __fmul_rn(w, 0.5f), hh = __fmul_rn(h, 0.5f);
            float4 bb = make_float4(__fsub_rn(cx, hw), __fsub_rn(cy, hh),
                                    __fadd_rn(cx, hw), __fadd_rn(cy, hh));
            rawG[b * CAP2 + p] = bb;
            float off = __fmul_rn((float)bj, 4096.0f);
            cboxG[b * CAP2 + p] = make_float4(__fadd_rn(bb.x, off), __fadd_rn(bb.y, off),
                                              __fadd_rn(bb.z, off), __fadd_rn(bb.w, off));
            cclsG[b * CAP2 + p] = (unsigned)bj;
        } else {
            rawG[b * CAP2 + p]  = make_float4(0.f, 0.f, 0.f, 0.f);
            cboxG[b * CAP2 + p] = make_float4(0.f, 0.f, 0.f, 0.f);
            cclsG[b * CAP2 + p] = 0u;
        }
        keysG[b * CAP2 + p] = keys[p];
    }
    if (tid == 0) ccnt[b] = c;
}

// 128 blocks (b,w): word-w suppression bits for all rows + transposed diagonal.
__global__ __launch_bounds__(256) void k_mask(const float4* __restrict__ cboxG,
                                              const int* __restrict__ ccnt,
                                              unsigned long long* __restrict__ maskG,
                                              unsigned long long* __restrict__ maskTG) {
    __shared__ float4 cb[CAP2];
    int b = blockIdx.x >> 3, w = blockIdx.x & 7;
    int tid = threadIdx.x;
    cb[tid] = cboxG[b * CAP2 + tid];
    cb[256 + tid] = cboxG[b * CAP2 + 256 + tid];
    __syncthreads();
    int c = min(ccnt[b], CAP2);
    int jbase = w << 6;
    for (int i = tid; i < CAP2; i += 256) {
        unsigned long long m = 0ULL;
        if (i < c && i < jbase + 63) {
            float4 ci = cb[i];
            float a1 = __fmul_rn(__fsub_rn(ci.z, ci.x), __fsub_rn(ci.w, ci.y));
#pragma unroll 4
            for (int jj = 0; jj < 64; ++jj) {
                int j = jbase + jj;
                float4 cj = cb[j];
                float ltx = fmaxf(ci.x, cj.x), lty = fmaxf(ci.y, cj.y);
                float rbx = fminf(ci.z, cj.z), rby = fminf(ci.w, cj.w);
                float ww = fmaxf(__fsub_rn(rbx, ltx), 0.0f);
                float hh = fmaxf(__fsub_rn(rby, lty), 0.0f);
                float inter = __fmul_rn(ww, hh);
                if (j > i && inter > 0.0f) {
                    float a2 = __fmul_rn(__fsub_rn(cj.z, cj.x), __fsub_rn(cj.w, cj.y));
                    float denom = __fadd_rn(__fsub_rn(__fadd_rn(a1, a2), inter), 1e-9f);
                    if (inter / denom > IOU_T) m |= (1ULL << jj);
                }
            }
        }
        maskG[((size_t)(b * CAP2 + i)) * 8 + w] = m;
    }
    // transposed diagonal: column l holds bits of earlier same-word suppressors.
    // IoU operand order identical to row-major (a1 from row i, a2 from col l).
    if (tid < 64) {
        int l = tid, p = jbase + l;
        unsigned long long m = 0ULL;
        if (p < c) {
            float4 cl = cb[p];
            float a2 = __fmul_rn(__fsub_rn(cl.z, cl.x), __fsub_rn(cl.w, cl.y));
            for (int ii = 0; ii < 64; ++ii) {
                float4 ci = cb[jbase + ii];
                float ltx = fmaxf(ci.x, cl.x), lty = fmaxf(ci.y, cl.y);
                float rbx = fminf(ci.z, cl.z), rby = fminf(ci.w, cl.w);
                float ww = fmaxf(__fsub_rn(rbx, ltx), 0.0f);
                float hh = fmaxf(__fsub_rn(rby, lty), 0.0f);
                float inter = __fmul_rn(ww, hh);
                if (ii < l && inter > 0.0f) {
                    float a1 = __fmul_rn(__fsub_rn(ci.z, ci.x), __fsub_rn(ci.w, ci.y));
                    float denom = __fadd_rn(__fsub_rn(__fadd_rn(a1, a2), inter), 1e-9f);
                    if (inter / denom > IOU_T) m |= (1ULL << ii);
                }
            }
        }
        maskTG[((size_t)(b * 8 + w)) * 64 + l] = m;
    }
}

// 16 blocks x 1024: ballot-fixpoint greedy resolve (exact) + outputs.
__global__ __launch_bounds__(NT) void k_fin(const float* __restrict__ logits,
                                            const unsigned long long* __restrict__ keysG,
                                            const float4* __restrict__ rawG,
                                            const unsigned* __restrict__ cclsG,
                                            const int* __restrict__ ccnt,
                                            const unsigned long long* __restrict__ maskG,
                                            const unsigned long long* __restrict__ maskTG,
                                            float* __restrict__ out) {
    __shared__ unsigned long long keepm_s[8];
    __shared__ unsigned kidx[64];
    __shared__ unsigned rowsrc_s[MAXDET];
    __shared__ int s_kept;

    int b = blockIdx.x, tid = threadIdx.x;
    int c = min(ccnt[b], CAP2);

    if (tid < 64) {
        int lane = tid;
        unsigned long long remq = 0ULL;  // lane q<8 owns rem word q
        int kept = 0;
        for (int w = 0; w < 8; ++w) {
            int base = w << 6;
            unsigned long long tw = __shfl(remq, w);
            bool pre = ((tw >> lane) & 1ULL) != 0ULL;
            bool validl = (base + lane) < c;
            unsigned long long Cl = maskTG[((size_t)(b * 8 + w)) * 64 + lane];
            unsigned long long initK = __ballot(validl && !pre);
            unsigned long long K = initK;
            // fixpoint: odd/even iterates sandwich the greedy set; exact on converge
            for (int it = 0; it < 64; ++it) {
                bool sup = (Cl & K & ((1ULL << lane) - 1ULL)) != 0ULL;
                unsigned long long K2 = initK & __ballot(!sup);
                if (K2 == K) break;
                K = K2;
            }
            // truncate to MAXDET total (reference scans exactly 300 picks)
            int limit = MAXDET - kept;
            int nk = __popcll(K);
            if (nk > limit) {
                if (limit <= 0) K = 0ULL;
                else {
                    int pref = __popcll(K & ((2ULL << lane) - 1ULL));  // bits 0..lane
                    bool el = ((K >> lane) & 1ULL) && (pref <= limit);
                    K = __ballot(el);
                }
            }
            kept += __popcll(K);
            if (lane == 0) keepm_s[w] = K;
            // cross-word rem update: 64 lanes fetch kept rows' words in parallel
            if (K != 0ULL && w < 7) {
                if ((K >> lane) & 1ULL) {
                    int r = __popcll(K & ((1ULL << lane) - 1ULL));
                    kidx[r] = (unsigned)lane;
                }
                __builtin_amdgcn_s_waitcnt(0);
                int nkk = __popcll(K);
                int q = lane & 7, slot = lane >> 3;
                unsigned long long acc = 0ULL;
                for (int t = slot; t < nkk; t += 8)
                    acc |= maskG[((size_t)(b * CAP2 + base + (int)kidx[t])) * 8 + q];
                acc |= __shfl_xor(acc, 8);
                acc |= __shfl_xor(acc, 16);
                acc |= __shfl_xor(acc, 32);
                if (slot == 0) remq |= acc;
            }
        }
        if (lane == 0) s_kept = kept;
    }
    __syncthreads();
    int kept = s_kept;

    float* dets = out;
    float* lg   = out + (size_t)BB * MAXDET * 6;
    float* kpo  = lg  + (size_t)BB * MAXDET * NCLS;

    // rank-scatter kept rows directly to dets; record source indices
    for (int p = tid; p < CAP2; p += NT) {
        if (p < c) {
            int w = p >> 6, bitp = p & 63;
            unsigned long long kw = keepm_s[w];
            if ((kw >> bitp) & 1ULL) {
                int rank = __popcll(kw & ((1ULL << bitp) - 1ULL));
                for (int q = 0; q < w; ++q) rank += __popcll(keepm_s[q]);
                if (rank < MAXDET) {
                    float4 bb = rawG[b * CAP2 + p];
                    unsigned long long key = keysG[b * CAP2 + p];
                    float* dr = dets + ((size_t)b * MAXDET + rank) * 6;
                    dr[0] = bb.x; dr[1] = bb.y; dr[2] = bb.z; dr[3] = bb.w;
                    dr[4] = __uint_as_float((unsigned)(key >> 32));
                    dr[5] = (float)cclsG[b * CAP2 + p];
                    rowsrc_s[rank] = 0xFFFFFFFFu - (unsigned)key;
                }
            }
        }
    }
    for (int i = tid; i < MAXDET; i += NT) {
        if (i >= kept) {
            float* dr = dets + ((size_t)b * MAXDET + i) * 6;
#pragma unroll
            for (int q = 0; q < 6; ++q) dr[q] = 0.0f;
        }
        kpo[b * MAXDET + i] = (i < kept) ? 1.0f : 0.0f;
    }
    __syncthreads();
    for (int i = tid; i < MAXDET * NCLS; i += NT) {
        int t = i / NCLS, col = i - t * NCLS;
        float v = 0.0f;
        if (t < kept) v = logits[((size_t)b * NN + rowsrc_s[t]) * NCLS + col];
        lg[(size_t)b * MAXDET * NCLS + i] = v;
    }
}

extern "C" void kernel_launch(void* const* d_in, const int* in_sizes, int n_in,
                              void* d_out, int out_size, void* d_ws, size_t ws_size,
                              hipStream_t stream) {
    const float* pred   = (const float*)d_in[0];
    const float* logits = (const float*)d_in[1];
    float* out = (float*)d_out;
    char* ws = (char*)d_ws;

    float* scr = (float*)ws;
    unsigned long long* keysG  = (unsigned long long*)(ws + OFF_KEYS);
    float4* cboxG              = (float4*)(ws + OFF_CBOX);
    float4* rawG               = (float4*)(ws + OFF_RAW);
    unsigned* cclsG            = (unsigned*)(ws + OFF_CCLS);
    int* ccnt                  = (int*)(ws + OFF_CCNT);
    unsigned long long* maskG  = (unsigned long long*)(ws + OFF_MASK);
    unsigned long long* maskTG = (unsigned long long*)(ws + OFF_MASKT);

    k_pre<<<6300, 256, 0, stream>>>(pred, scr);                 // 403200/64 exact
    k_sel<<<BB, NT, 0, stream>>>(pred, scr, keysG, cboxG, rawG, cclsG, ccnt);
    k_mask<<<BB * 8, 256, 0, stream>>>(cboxG, ccnt, maskG, maskTG);
    k_fin<<<BB, NT, 0, stream>>>(logits, keysG, rawG, cclsG, ccnt, maskG, maskTG, out);
}